// Round 3
// baseline (28.826 us; speedup 1.0000x reference)
//
#include <hip/hip_runtime.h>

// Problem constants (match reference setup_inputs)
#define BB 4
#define HH 1024
#define WW 1024
#define NC 12
#define GD 16
#define GH 16
#define GW 8

// LDS slab: H[x][z][c] packed as half2( F(x,z,c), F(x,z+1,c) ) — z-duplicated
// f16 so one dword read gives both z corners of a channel.
// z-stride 12 dwords, x-stride 196 dwords (pad +4): every corner base
// (x*196 + z*12) is a multiple of 4 dwords -> 16B-aligned ds_read_b128.
// Bank-quad index = (x + 3z) mod 8 -> uniform spread over the 8 quad groups.
#define ZSD 12
#define XSD 196
#define HSZ (GW * XSD)   // 1568 dwords = 6272 B

typedef _Float16 half2v __attribute__((ext_vector_type(2)));

__device__ __forceinline__ float zlerp(uint u, _Float16 wzh) {
    union { uint v; half2v h; } c;
    c.v = u;
    _Float16 lo = c.h.x, hi = c.h.y;
    _Float16 r = lo + wzh * (hi - lo);
    return (float)r;
}

__global__ __launch_bounds__(256) void bgrid_row(const float* __restrict__ img,
                                                 const float* __restrict__ grid,
                                                 float* __restrict__ out)
{
    const int y = blockIdx.x;
    const int b = blockIdx.y;
    const int tid = threadIdx.x;

    __shared__ __align__(16) uint H[HSZ];

    // ---- per-row y interpolation constants (block-uniform) ----
    float uy = fminf(y * (15.0f / 1023.0f), 15.0f);
    int y0 = (int)uy;
    int y1 = min(y0 + 1, GH - 1);
    float wy = uy - (float)y0;

    // ---- stage y-lerped, z-dup'd f16 slab into LDS ----
    const float* gb = grid + (size_t)b * (NC * GD * GH * GW); // [c][z][y][x]
#pragma unroll
    for (int j = 0; j < 6; j++) {
        int t = tid + 256 * j;          // 0..1535 = 8x * 16z * 12c
        int x = t & 7;
        int z = (t >> 3) & 15;
        int c = t >> 7;
        int zp = min(z + 1, GD - 1);
        const float* bc = gb + (size_t)c * (GD * GH * GW) + x;
        float a0 = bc[z  * (GH * GW) + y0 * GW];
        float a1 = bc[z  * (GH * GW) + y1 * GW];
        float c0 = bc[zp * (GH * GW) + y0 * GW];
        float c1 = bc[zp * (GH * GW) + y1 * GW];
        float f0 = fmaf(wy, a1 - a0, a0);
        float f1 = fmaf(wy, c1 - c0, c0);
        union { half2v h; uint u; } pk;
        pk.h = half2v{(_Float16)f0, (_Float16)f1};
        H[x * XSD + z * ZSD + c] = pk.u;
    }
    __syncthreads();

    // ---- process 4 pixels per thread with float4 I/O ----
    const size_t plane = (size_t)HH * WW;
    const size_t rowoff = (size_t)b * 3 * plane + (size_t)y * WW;
    const float4 r4 = *(const float4*)(img + rowoff + 4 * tid);
    const float4 g4 = *(const float4*)(img + rowoff + plane + 4 * tid);
    const float4 b4 = *(const float4*)(img + rowoff + 2 * plane + 4 * tid);

    float4 o0, o1, o2;
    float* o0p = (float*)&o0; float* o1p = (float*)&o1; float* o2p = (float*)&o2;
    const float* rp = (const float*)&r4;
    const float* gp = (const float*)&g4;
    const float* bp = (const float*)&b4;

#pragma unroll
    for (int p = 0; p < 4; p++) {
        const int px = 4 * tid + p;
        const float r = rp[p], g = gp[p], bl = bp[p];

        float ux = fminf(px * (7.0f / 1023.0f), 7.0f);
        int x0 = (int)ux;
        int x1 = min(x0 + 1, GW - 1);
        float wx = ux - (float)x0;

        float lum = 0.299f * r + 0.587f * g + 0.114f * bl;
        float uz = fminf(fmaxf(lum * 15.0f, 0.0f), 15.0f);
        int z0 = (int)uz;
        float wz = uz - (float)z0;
        _Float16 wzh = (_Float16)wz;

        const int bx0 = x0 * XSD + z0 * ZSD;
        const int bx1 = x1 * XSD + z0 * ZSD;
        const uint4* qa = (const uint4*)&H[bx0];
        const uint4* qb = (const uint4*)&H[bx1];
        uint va[12], vb[12];
        *(uint4*)(va + 0) = qa[0];
        *(uint4*)(va + 4) = qa[1];
        *(uint4*)(va + 8) = qa[2];
        *(uint4*)(vb + 0) = qb[0];
        *(uint4*)(vb + 4) = qb[1];
        *(uint4*)(vb + 8) = qb[2];

        float cf[12];
#pragma unroll
        for (int c = 0; c < 12; c++) {
            float v0 = zlerp(va[c], wzh);
            float v1 = zlerp(vb[c], wzh);
            cf[c] = fmaf(wx, v1 - v0, v0);
        }

        float v0 = cf[0] * r + cf[1] * g + cf[2] * bl + cf[9];
        float v1 = cf[3] * r + cf[4] * g + cf[5] * bl + cf[10];
        float v2 = cf[6] * r + cf[7] * g + cf[8] * bl + cf[11];
        o0p[p] = fminf(fmaxf(v0, 0.0f), 1.0f);
        o1p[p] = fminf(fmaxf(v1, 0.0f), 1.0f);
        o2p[p] = fminf(fmaxf(v2, 0.0f), 1.0f);
    }

    *(float4*)(out + rowoff + 4 * tid) = o0;
    *(float4*)(out + rowoff + plane + 4 * tid) = o1;
    *(float4*)(out + rowoff + 2 * plane + 4 * tid) = o2;
}

extern "C" void kernel_launch(void* const* d_in, const int* in_sizes, int n_in,
                              void* d_out, int out_size, void* d_ws, size_t ws_size,
                              hipStream_t stream) {
    const float* grid  = (const float*)d_in[0];
    const float* image = (const float*)d_in[1];
    float* out = (float*)d_out;

    dim3 blk(256);
    dim3 grd(HH, BB);   // one block per (row, batch)
    bgrid_row<<<grd, blk, 0, stream>>>(image, grid, out);
}

// Round 4
// 24.761 us; speedup vs baseline: 1.1642x; 1.1642x over previous
//
#include <hip/hip_runtime.h>

// Problem constants (match reference setup_inputs)
#define BB 4
#define HH 1024
#define WW 1024
#define NC 12
#define GD 16
#define GH 16
#define GW 8

// LDS slab H[x][z][c]: one dword = half2( F(x,z,c), F(x,z+1,c) )  (z-duplicated
// f16, y already lerped). z-stride 12 dwords (48B, 16B-aligned), x-stride 196
// dwords (784B; 49 quad-groups -> neighbor x lands in adjacent bank group).
// Per-instr bank spread: quad-group = (49*x + 3*z + q) mod 8; random z covers
// all 8 groups; colliding z pairs (z, z+8) mostly broadcast/2-way => ~free.
#define ZSD 12
#define XSD 196
#define HSZ (GW * XSD)   // 1568 dwords = 6272 B

typedef _Float16 h2 __attribute__((ext_vector_type(2)));
union HU { uint u; h2 h; };

// x-lerp both z corners in packed f16, then z-lerp in f32.
#define CH(ua_, ub_, dst_) do {                                   \
    HU A_, B_; A_.u = (ua_); B_.u = (ub_);                        \
    h2 m_ = A_.h + wx2 * (B_.h - A_.h);                           \
    float m0_ = (float)m_.x;                                      \
    float m1_ = (float)m_.y;                                      \
    dst_ = fmaf(wz, m1_ - m0_, m0_);                              \
} while (0)

__global__ __launch_bounds__(256) void bgrid_row(const float* __restrict__ img,
                                                 const float* __restrict__ grid,
                                                 float* __restrict__ out)
{
    const int y = blockIdx.x;
    const int b = blockIdx.y;
    const int tid = threadIdx.x;

    __shared__ __align__(16) uint H[HSZ];

    // ---- per-row y interpolation constants (block-uniform) ----
    float uy = fminf(y * (15.0f / 1023.0f), 15.0f);
    int y0 = (int)uy;
    int y1 = min(y0 + 1, GH - 1);
    float wy = uy - (float)y0;

    // ---- stage y-lerped, z-dup'd f16 slab into LDS ----
    const float* gb = grid + (size_t)b * (NC * GD * GH * GW); // [c][z][y][x]
#pragma unroll
    for (int j = 0; j < 6; j++) {
        int t = tid + 256 * j;          // 0..1535 = 8x * 16z * 12c
        int x = t & 7;
        int z = (t >> 3) & 15;
        int c = t >> 7;
        int zp = min(z + 1, GD - 1);
        const float* bc = gb + c * (GD * GH * GW) + x;
        float a0 = bc[(z  * GH + y0) * GW];
        float a1 = bc[(z  * GH + y1) * GW];
        float c0 = bc[(zp * GH + y0) * GW];
        float c1 = bc[(zp * GH + y1) * GW];
        float f0 = fmaf(wy, a1 - a0, a0);
        float f1 = fmaf(wy, c1 - c0, c0);
        HU pk;
        pk.h = h2{(_Float16)f0, (_Float16)f1};
        H[x * XSD + z * ZSD + c] = pk.u;
    }
    __syncthreads();

    // ---- process 4 pixels per thread with float4 I/O ----
    const size_t plane = (size_t)HH * WW;
    const size_t rowoff = (size_t)b * 3 * plane + (size_t)y * WW;
    const float4 r4 = *(const float4*)(img + rowoff + 4 * tid);
    const float4 g4 = *(const float4*)(img + rowoff + plane + 4 * tid);
    const float4 b4 = *(const float4*)(img + rowoff + 2 * plane + 4 * tid);

    float4 o0, o1, o2;
    float* o0p = (float*)&o0; float* o1p = (float*)&o1; float* o2p = (float*)&o2;
    const float* rp = (const float*)&r4;
    const float* gp = (const float*)&g4;
    const float* bp = (const float*)&b4;

#pragma unroll
    for (int p = 0; p < 4; p++) {
        const int px = 4 * tid + p;
        const float r = rp[p], g = gp[p], bl = bp[p];

        float ux = fminf(px * (7.0f / 1023.0f), 7.0f);
        int x0 = (int)ux;
        int x1 = min(x0 + 1, GW - 1);
        float wx = ux - (float)x0;
        _Float16 wxh = (_Float16)wx;
        h2 wx2 = h2{wxh, wxh};

        float lum = 0.299f * r + 0.587f * g + 0.114f * bl;
        float uz = fminf(fmaxf(lum * 15.0f, 0.0f), 15.0f);
        int z0 = (int)uz;
        float wz = uz - (float)z0;

        const uint* pa = &H[x0 * XSD + z0 * ZSD];
        const uint* pb = &H[x1 * XSD + z0 * ZSD];
        const uint4 qa0 = ((const uint4*)pa)[0];
        const uint4 qa1 = ((const uint4*)pa)[1];
        const uint4 qa2 = ((const uint4*)pa)[2];
        const uint4 qb0 = ((const uint4*)pb)[0];
        const uint4 qb1 = ((const uint4*)pb)[1];
        const uint4 qb2 = ((const uint4*)pb)[2];

        float c0, c1, c2, c3, c4, c5, c6, c7, c8, c9, c10, c11;
        CH(qa0.x, qb0.x, c0);  CH(qa0.y, qb0.y, c1);
        CH(qa0.z, qb0.z, c2);  CH(qa0.w, qb0.w, c3);
        CH(qa1.x, qb1.x, c4);  CH(qa1.y, qb1.y, c5);
        CH(qa1.z, qb1.z, c6);  CH(qa1.w, qb1.w, c7);
        CH(qa2.x, qb2.x, c8);  CH(qa2.y, qb2.y, c9);
        CH(qa2.z, qb2.z, c10); CH(qa2.w, qb2.w, c11);

        float v0 = c0 * r + c1 * g + c2  * bl + c9;
        float v1 = c3 * r + c4 * g + c5  * bl + c10;
        float v2 = c6 * r + c7 * g + c8  * bl + c11;
        o0p[p] = fminf(fmaxf(v0, 0.0f), 1.0f);
        o1p[p] = fminf(fmaxf(v1, 0.0f), 1.0f);
        o2p[p] = fminf(fmaxf(v2, 0.0f), 1.0f);
    }

    *(float4*)(out + rowoff + 4 * tid) = o0;
    *(float4*)(out + rowoff + plane + 4 * tid) = o1;
    *(float4*)(out + rowoff + 2 * plane + 4 * tid) = o2;
}

extern "C" void kernel_launch(void* const* d_in, const int* in_sizes, int n_in,
                              void* d_out, int out_size, void* d_ws, size_t ws_size,
                              hipStream_t stream) {
    const float* grid  = (const float*)d_in[0];
    const float* image = (const float*)d_in[1];
    float* out = (float*)d_out;

    dim3 blk(256);
    dim3 grd(HH, BB);   // one block per (row, batch)
    bgrid_row<<<grd, blk, 0, stream>>>(image, grid, out);
}